// Round 2
// 266.691 us; speedup vs baseline: 1.0495x; 1.0495x over previous
//
#include <hip/hip_runtime.h>
#include <math.h>

#define DIM 96
#define NE 6
#define NB 8
#define H 192
#define W 192
#define HW (H * W)
#define NQ 4            // pool partial quarters
#define QF4 (HW / 4 / NQ)  // 2304 float4 per quarter

// ---------------- Kernel A: partial max+sum per (b,c,quarter) ----------------
__global__ __launch_bounds__(256) void pool_partial(const float* __restrict__ x,
                                                    float* __restrict__ pmax,
                                                    float* __restrict__ psum) {
    int bc = blockIdx.x;       // 0..767
    int q = blockIdx.y;        // 0..3
    const float4* xp = (const float4*)(x + (size_t)bc * HW) + q * QF4;
    int tid = threadIdx.x;
    float vmax = -INFINITY, vsum = 0.f;
    for (int i = tid; i < QF4; i += 256) {
        float4 v = xp[i];
        vmax = fmaxf(vmax, fmaxf(fmaxf(v.x, v.y), fmaxf(v.z, v.w)));
        vsum += v.x + v.y + v.z + v.w;
    }
    for (int off = 32; off; off >>= 1) {
        vmax = fmaxf(vmax, __shfl_down(vmax, off, 64));
        vsum += __shfl_down(vsum, off, 64);
    }
    __shared__ float smax[4], ssum[4];
    if ((tid & 63) == 0) { smax[tid >> 6] = vmax; ssum[tid >> 6] = vsum; }
    __syncthreads();
    if (tid == 0) {
        float m = smax[0], s = ssum[0];
        for (int w = 1; w < 4; ++w) { m = fmaxf(m, smax[w]); s += ssum[w]; }
        pmax[q * (NB * DIM) + bc] = m;
        psum[q * (NB * DIM) + bc] = s;
    }
}

// ---------------- Kernel B: gate (parallel dots from LDS) ----------------
__global__ __launch_bounds__(128) void gate_kernel(const float* __restrict__ pmax,
                                                   const float* __restrict__ psum,
                                                   const float* __restrict__ w_fc0,
                                                   const float* __restrict__ b_fc0,
                                                   const float* __restrict__ w_fc1,
                                                   const float* __restrict__ b_fc1,
                                                   float* __restrict__ cof) {
    __shared__ float sp[NB * DIM];       // pooled
    __shared__ float sw1[NE * DIM], sw0[NE * DIM];
    __shared__ float z1s[NB * NE], z0s[NB * NE];
    int tid = threadIdx.x;
    // merge pool partials -> pooled = max + mean
    for (int i = tid; i < NB * DIM; i += 128) {
        float m = pmax[i], s = psum[i];
        for (int q = 1; q < NQ; ++q) {
            m = fmaxf(m, pmax[q * (NB * DIM) + i]);
            s += psum[q * (NB * DIM) + i];
        }
        sp[i] = m + s * (1.0f / (float)HW);
    }
    for (int i = tid; i < NE * DIM; i += 128) {
        sw1[i] = w_fc1[i];
        sw0[i] = w_fc0[i];
    }
    __syncthreads();
    if (tid < 2 * NB * NE) {             // 96 threads: one dot each
        int pair = (tid < NB * NE) ? tid : tid - NB * NE;
        int b = pair / NE, e = pair - b * NE;
        const float* wp = ((tid < NB * NE) ? sw1 : sw0) + e * DIM;
        float z = (tid < NB * NE) ? b_fc1[e] : b_fc0[e];
        const float* pp = sp + b * DIM;
        for (int i = 0; i < DIM; ++i) z = fmaf(pp[i], wp[i], z);
        if (tid < NB * NE) z1s[pair] = z; else z0s[pair] = z;
    }
    __syncthreads();
    if (tid < NB) {
        int b = tid;
        float g[NE], noise[NE];
        for (int e = 0; e < NE; ++e) {
            float z1 = z1s[b * NE + e], z0 = z0s[b * NE + e];
            g[e] = (z1 > 0.f) ? z1 : 0.2f * z1;                 // leaky_relu 0.2
            noise[e] = (z0 > 20.f) ? z0 : log1pf(expf(z0));     // softplus
        }
        float mu = 0.f;
        for (int e = 0; e < NE; ++e) mu += noise[e];
        mu *= (1.0f / NE);
        float var = 0.f;
        for (int e = 0; e < NE; ++e) { float d = noise[e] - mu; var += d * d; }
        var *= (1.0f / (NE - 1));                               // ddof=1
        float sd = sqrtf(var);
        float scores[NE];
        for (int e = 0; e < NE; ++e) scores[e] = g[e] + (noise[e] - mu) / sd;
        bool chosen[NE] = {false, false, false, false, false, false};
        for (int k = 0; k < 3; ++k) {                           // top-3, ties -> lowest idx
            float best = -INFINITY; int bi = 0;
            for (int e = 0; e < NE; ++e)
                if (!chosen[e] && scores[e] > best) { best = scores[e]; bi = e; }
            chosen[bi] = true;
        }
        float m = -INFINITY;
        for (int e = 0; e < NE; ++e) if (chosen[e]) m = fmaxf(m, g[e]);
        float s = 0.f;
        for (int e = 0; e < NE; ++e) if (chosen[e]) s += expf(g[e] - m);
        float inv = 1.0f / s;
        for (int e = 0; e < NE; ++e)
            cof[b * NE + e] = chosen[e] ? expf(g[e] - m) * inv : 0.f;
    }
}

// ---------------- Kernel C: fused top-k expert dwconv-relu-dwconv (v2) ----------------
// Full-width stripe: 192 cols x TY rows per block; 4 waves x RPW rows; 3 cols/lane.
// ys kept in registers (3-row x 5-col window per expert), neighbors via shfl.
// ys col -1 / 192 and row -1 / H are image borders -> exactly 0 (conv2 zero-pad).
#define TY 32
#define RPW 8                 // rows per wave
#define SW 200                // LDS row stride (floats); x col i stored at i+4
#define XROWS (TY + 4)        // 36 staged rows

// 3x3 FMA chain, association identical to v1 kernel:
//   s = w0*A0 + (w1*A1 + (w2*A2 + bb)); s = w3*B0 + (w4*B1 + (w5*B2 + s)); ...
__device__ __forceinline__ float c3(const float* Wt, float bb,
                                    const float* A, const float* B,
                                    const float* Cc, int o) {
    float s = fmaf(Wt[2], A[o + 2], bb);
    s = fmaf(Wt[1], A[o + 1], s);
    s = fmaf(Wt[0], A[o], s);
    s = fmaf(Wt[5], B[o + 2], s);
    s = fmaf(Wt[4], B[o + 1], s);
    s = fmaf(Wt[3], B[o], s);
    s = fmaf(Wt[8], Cc[o + 2], s);
    s = fmaf(Wt[7], Cc[o + 1], s);
    s = fmaf(Wt[6], Cc[o], s);
    return s;
}

__global__ __launch_bounds__(256) void moe_kernel(const float* __restrict__ x,
                                                  const float* __restrict__ ew1,
                                                  const float* __restrict__ eb1,
                                                  const float* __restrict__ ew2,
                                                  const float* __restrict__ eb2,
                                                  const float* __restrict__ cof,
                                                  float* __restrict__ out) {
    __shared__ float xs[XROWS * SW];     // 36*200*4 = 28800 B
    const int sb = blockIdx.x;           // stripe 0..5
    const int c = blockIdx.y;
    const int b = blockIdx.z;
    const int ty0 = sb * TY;
    const int tid = threadIdx.x;
    const int lane = tid & 63;
    const int wv = tid >> 6;

    // ---- zero the 4-col aprons (xi 0..3 and 196..199), one b128 each ----
    if (tid < 2 * XROWS) {
        int r = tid >> 1;
        int side = tid & 1;
        *(float4*)&xs[r * SW + side * 196] = make_float4(0.f, 0.f, 0.f, 0.f);
    }

    // ---- stage 36 rows x 192 cols as float4 (48 per row), flat over 256 threads ----
    const float* xp = x + ((size_t)(b * DIM + c)) * HW;
    #pragma unroll
    for (int it = 0; it < 7; ++it) {
        int f = tid + it * 256;
        if (f < XROWS * 48) {
            int r = f / 48;
            int k = f - r * 48;
            int gh = ty0 + r - 2;
            float4 v = make_float4(0.f, 0.f, 0.f, 0.f);
            if (gh >= 0 && gh < H) v = *(const float4*)(xp + (size_t)gh * W + k * 4);
            *(float4*)&xs[r * SW + 4 + k * 4] = v;
        }
    }

    // ---- compact the (always exactly 3) chosen experts; hoist to SGPR ----
    const float* cofb = cof + b * NE;
    int e0 = 0, e1 = 0, e2 = 0;
    float q0 = 0.f, q1 = 0.f, q2 = 0.f;
    int n = 0;
    #pragma unroll
    for (int e = 0; e < NE; ++e) {
        float ce = cofb[e];
        if (ce != 0.f) {
            if (n == 0)      { e0 = e; q0 = ce; }
            else if (n == 1) { e1 = e; q1 = ce; }
            else if (n == 2) { e2 = e; q2 = ce; }
            ++n;
        }
    }
    e0 = __builtin_amdgcn_readfirstlane(e0);
    e1 = __builtin_amdgcn_readfirstlane(e1);
    e2 = __builtin_amdgcn_readfirstlane(e2);
    q0 = __int_as_float(__builtin_amdgcn_readfirstlane(__float_as_int(q0)));
    q1 = __int_as_float(__builtin_amdgcn_readfirstlane(__float_as_int(q1)));
    q2 = __int_as_float(__builtin_amdgcn_readfirstlane(__float_as_int(q2)));

    const int eidx[3] = { e0, e1, e2 };
    const float qv[3] = { q0, q1, q2 };
    float W1[3][9], W2[3][9], B1[3], B2[3], CE[3];
    #pragma unroll
    for (int t = 0; t < 3; ++t) {
        const int e = eidx[t];
        const float* p1 = ew1 + (size_t)(e * DIM + c) * 9;
        const float* p2 = ew2 + (size_t)(e * DIM + c) * 9;
        #pragma unroll
        for (int k = 0; k < 9; ++k) { W1[t][k] = p1[k]; W2[t][k] = p2[k]; }
        B1[t] = eb1[e * DIM + c];
        B2[t] = eb2[e * DIM + c];
        CE[t] = qv[t];
    }

    __syncthreads();                     // xs staged (single barrier in kernel)

    const int r0 = ty0 + wv * RPW;       // first conv2 output row of this wave
    const int lbase = (wv * RPW) * SW + 3 * lane + 3;  // xs idx of col (3*lane-1), row r0-2
    const bool l0 = (lane == 0);
    const bool l63 = (lane == 63);

    float X[3][5];                       // xs window: 3 rows x 5 cols (3c-1..3c+3)
    float Y[3][3][5];                    // per expert: 3 ys rows x 5 cols
    #pragma unroll
    for (int k = 0; k < 5; ++k) X[0][k] = xs[lbase + k];           // row r0-2
    #pragma unroll
    for (int k = 0; k < 5; ++k) X[1][k] = xs[lbase + SW + k];      // row r0-1

    float* op = out + ((size_t)(b * DIM + c)) * HW + (size_t)r0 * W + 3 * lane;

    #pragma unroll
    for (int j = 0; j < RPW + 2; ++j) {  // ys row ry = r0-1+j; out row r0+j-2 for j>=2
        float* xN = X[(j + 2) % 3];
        #pragma unroll
        for (int k = 0; k < 5; ++k) xN[k] = xs[lbase + (j + 2) * SW + k];  // row r0+j
        const float* xA = X[j % 3];          // row ry-1
        const float* xB = X[(j + 1) % 3];    // row ry
        const float* xC = xN;                // row ry+1
        float a0 = 0.f, a1 = 0.f, a2 = 0.f;
        #pragma unroll
        for (int t = 0; t < 3; ++t) {
            // conv1 + bias + relu, 3 cols
            float y0 = c3(W1[t], B1[t], xA, xB, xC, 0);
            float y1 = c3(W1[t], B1[t], xA, xB, xC, 1);
            float y2 = c3(W1[t], B1[t], xA, xB, xC, 2);
            y0 = fmaxf(y0, 0.f); y1 = fmaxf(y1, 0.f); y2 = fmaxf(y2, 0.f);
            if (j == 0 || j == RPW + 1) {    // only edge rows can be out of image
                int ry = r0 - 1 + j;
                if (ry < 0 || ry >= H) { y0 = 0.f; y1 = 0.f; y2 = 0.f; }  // conv2 zero-pad
            }
            float yl = __shfl_up(y2, 1);     // neighbor col 3*lane-1
            float yr = __shfl_down(y0, 1);   // neighbor col 3*lane+3
            if (l0) yl = 0.f;                // ys col -1  (image border) == 0
            if (l63) yr = 0.f;               // ys col 192 (image border) == 0
            float* yw = Y[t][j % 3];
            yw[0] = yl; yw[1] = y0; yw[2] = y1; yw[3] = y2; yw[4] = yr;
            if (j >= 2) {
                const float* pA = Y[t][(j + 1) % 3];  // ys row ro-1
                const float* pB = Y[t][(j + 2) % 3];  // ys row ro
                const float* pC = yw;                 // ys row ro+1
                float s0 = c3(W2[t], B2[t], pA, pB, pC, 0);
                float s1 = c3(W2[t], B2[t], pA, pB, pC, 1);
                float s2 = c3(W2[t], B2[t], pA, pB, pC, 2);
                a0 = fmaf(CE[t], s0, a0);
                a1 = fmaf(CE[t], s1, a1);
                a2 = fmaf(CE[t], s2, a2);
            }
        }
        if (j >= 2) {
            op[0] = a0; op[1] = a1; op[2] = a2;
            op += W;
        }
    }
}

extern "C" void kernel_launch(void* const* d_in, const int* in_sizes, int n_in,
                              void* d_out, int out_size, void* d_ws, size_t ws_size,
                              hipStream_t stream) {
    const float* x     = (const float*)d_in[0];
    const float* w_fc0 = (const float*)d_in[1];
    const float* b_fc0 = (const float*)d_in[2];
    const float* w_fc1 = (const float*)d_in[3];
    const float* b_fc1 = (const float*)d_in[4];
    const float* ew1   = (const float*)d_in[5];
    const float* eb1   = (const float*)d_in[6];
    const float* ew2   = (const float*)d_in[7];
    const float* eb2   = (const float*)d_in[8];
    float* out = (float*)d_out;

    float* pmax = (float*)d_ws;                       // NQ*768
    float* psum = pmax + NQ * NB * DIM;               // NQ*768
    float* cof  = psum + NQ * NB * DIM;               // 48

    dim3 pg(NB * DIM, NQ);
    pool_partial<<<pg, 256, 0, stream>>>(x, pmax, psum);
    gate_kernel<<<1, 128, 0, stream>>>(pmax, psum, w_fc0, b_fc0, w_fc1, b_fc1, cof);
    dim3 grid(H / TY, DIM, NB);                       // (6, 96, 8)
    moe_kernel<<<grid, 256, 0, stream>>>(x, ew1, eb1, ew2, eb2, cof, out);
}

// Round 3
// 257.334 us; speedup vs baseline: 1.0877x; 1.0364x over previous
//
#include <hip/hip_runtime.h>
#include <math.h>

#define DIM 96
#define NE 6
#define NB 8
#define H 192
#define W 192
#define HW (H * W)
#define NQ 4            // pool partial quarters
#define QF4 (HW / 4 / NQ)  // 2304 float4 per quarter

typedef float f2 __attribute__((ext_vector_type(2)));

// ---------------- Kernel A: partial max+sum per (b,c,quarter) ----------------
__global__ __launch_bounds__(256) void pool_partial(const float* __restrict__ x,
                                                    float* __restrict__ pmax,
                                                    float* __restrict__ psum) {
    int bc = blockIdx.x;       // 0..767
    int q = blockIdx.y;        // 0..3
    const float4* xp = (const float4*)(x + (size_t)bc * HW) + q * QF4;
    int tid = threadIdx.x;
    float vmax = -INFINITY, vsum = 0.f;
    for (int i = tid; i < QF4; i += 256) {
        float4 v = xp[i];
        vmax = fmaxf(vmax, fmaxf(fmaxf(v.x, v.y), fmaxf(v.z, v.w)));
        vsum += v.x + v.y + v.z + v.w;
    }
    for (int off = 32; off; off >>= 1) {
        vmax = fmaxf(vmax, __shfl_down(vmax, off, 64));
        vsum += __shfl_down(vsum, off, 64);
    }
    __shared__ float smax[4], ssum[4];
    if ((tid & 63) == 0) { smax[tid >> 6] = vmax; ssum[tid >> 6] = vsum; }
    __syncthreads();
    if (tid == 0) {
        float m = smax[0], s = ssum[0];
        for (int w = 1; w < 4; ++w) { m = fmaxf(m, smax[w]); s += ssum[w]; }
        pmax[q * (NB * DIM) + bc] = m;
        psum[q * (NB * DIM) + bc] = s;
    }
}

// ---------------- Kernel B: gate (parallel dots from LDS) ----------------
__global__ __launch_bounds__(128) void gate_kernel(const float* __restrict__ pmax,
                                                   const float* __restrict__ psum,
                                                   const float* __restrict__ w_fc0,
                                                   const float* __restrict__ b_fc0,
                                                   const float* __restrict__ w_fc1,
                                                   const float* __restrict__ b_fc1,
                                                   float* __restrict__ cof) {
    __shared__ float sp[NB * DIM];       // pooled
    __shared__ float sw1[NE * DIM], sw0[NE * DIM];
    __shared__ float z1s[NB * NE], z0s[NB * NE];
    int tid = threadIdx.x;
    // merge pool partials -> pooled = max + mean
    for (int i = tid; i < NB * DIM; i += 128) {
        float m = pmax[i], s = psum[i];
        for (int q = 1; q < NQ; ++q) {
            m = fmaxf(m, pmax[q * (NB * DIM) + i]);
            s += psum[q * (NB * DIM) + i];
        }
        sp[i] = m + s * (1.0f / (float)HW);
    }
    for (int i = tid; i < NE * DIM; i += 128) {
        sw1[i] = w_fc1[i];
        sw0[i] = w_fc0[i];
    }
    __syncthreads();
    if (tid < 2 * NB * NE) {             // 96 threads: one dot each
        int pair = (tid < NB * NE) ? tid : tid - NB * NE;
        int b = pair / NE, e = pair - b * NE;
        const float* wp = ((tid < NB * NE) ? sw1 : sw0) + e * DIM;
        float z = (tid < NB * NE) ? b_fc1[e] : b_fc0[e];
        const float* pp = sp + b * DIM;
        for (int i = 0; i < DIM; ++i) z = fmaf(pp[i], wp[i], z);
        if (tid < NB * NE) z1s[pair] = z; else z0s[pair] = z;
    }
    __syncthreads();
    if (tid < NB) {
        int b = tid;
        float g[NE], noise[NE];
        for (int e = 0; e < NE; ++e) {
            float z1 = z1s[b * NE + e], z0 = z0s[b * NE + e];
            g[e] = (z1 > 0.f) ? z1 : 0.2f * z1;                 // leaky_relu 0.2
            noise[e] = (z0 > 20.f) ? z0 : log1pf(expf(z0));     // softplus
        }
        float mu = 0.f;
        for (int e = 0; e < NE; ++e) mu += noise[e];
        mu *= (1.0f / NE);
        float var = 0.f;
        for (int e = 0; e < NE; ++e) { float d = noise[e] - mu; var += d * d; }
        var *= (1.0f / (NE - 1));                               // ddof=1
        float sd = sqrtf(var);
        float scores[NE];
        for (int e = 0; e < NE; ++e) scores[e] = g[e] + (noise[e] - mu) / sd;
        bool chosen[NE] = {false, false, false, false, false, false};
        for (int k = 0; k < 3; ++k) {                           // top-3, ties -> lowest idx
            float best = -INFINITY; int bi = 0;
            for (int e = 0; e < NE; ++e)
                if (!chosen[e] && scores[e] > best) { best = scores[e]; bi = e; }
            chosen[bi] = true;
        }
        float m = -INFINITY;
        for (int e = 0; e < NE; ++e) if (chosen[e]) m = fmaxf(m, g[e]);
        float s = 0.f;
        for (int e = 0; e < NE; ++e) if (chosen[e]) s += expf(g[e] - m);
        float inv = 1.0f / s;
        for (int e = 0; e < NE; ++e)
            cof[b * NE + e] = chosen[e] ? expf(g[e] - m) * inv : 0.f;
    }
}

// ---------------- Kernel C: fused top-k expert dwconv-relu-dwconv (v3: packed fp32) ----
// Full-width stripe: 192 cols x TY rows per block; 4 waves x RPW rows; 3 cols/lane.
// Experts (e0,e1) run as float2 halves through v_pk_fma_f32; e2 scalar.
// Per-expert FMA association identical to v2 -> bit-identical output.
#define TY 32
#define RPW 8                 // rows per wave
#define SW 200                // LDS row stride (floats); x col i stored at i+4
#define XROWS (TY + 4)        // 36 staged rows

__device__ __forceinline__ f2 splat2(float v) { f2 r; r.x = v; r.y = v; return r; }

// scalar 3x3 chain (association: w2*A2+bb innermost, rows A,B,C outward)
__device__ __forceinline__ float c3(const float* Wt, float bb,
                                    const float* A, const float* B,
                                    const float* Cc, int o) {
    float s = fmaf(Wt[2], A[o + 2], bb);
    s = fmaf(Wt[1], A[o + 1], s);
    s = fmaf(Wt[0], A[o], s);
    s = fmaf(Wt[5], B[o + 2], s);
    s = fmaf(Wt[4], B[o + 1], s);
    s = fmaf(Wt[3], B[o], s);
    s = fmaf(Wt[8], Cc[o + 2], s);
    s = fmaf(Wt[7], Cc[o + 1], s);
    s = fmaf(Wt[6], Cc[o], s);
    return s;
}

// packed pair-of-experts chain, x operands are splatted scalars (conv1)
__device__ __forceinline__ f2 c3p(const f2* Wt, f2 bb,
                                  const float* A, const float* B,
                                  const float* Cc, int o) {
    f2 s = __builtin_elementwise_fma(Wt[2], splat2(A[o + 2]), bb);
    s = __builtin_elementwise_fma(Wt[1], splat2(A[o + 1]), s);
    s = __builtin_elementwise_fma(Wt[0], splat2(A[o]), s);
    s = __builtin_elementwise_fma(Wt[5], splat2(B[o + 2]), s);
    s = __builtin_elementwise_fma(Wt[4], splat2(B[o + 1]), s);
    s = __builtin_elementwise_fma(Wt[3], splat2(B[o]), s);
    s = __builtin_elementwise_fma(Wt[8], splat2(Cc[o + 2]), s);
    s = __builtin_elementwise_fma(Wt[7], splat2(Cc[o + 1]), s);
    s = __builtin_elementwise_fma(Wt[6], splat2(Cc[o]), s);
    return s;
}

// packed chain with pair operands (conv2: ys halves are per-expert already)
__device__ __forceinline__ f2 c3q(const f2* Wt, f2 bb,
                                  const f2* A, const f2* B,
                                  const f2* Cc, int o) {
    f2 s = __builtin_elementwise_fma(Wt[2], A[o + 2], bb);
    s = __builtin_elementwise_fma(Wt[1], A[o + 1], s);
    s = __builtin_elementwise_fma(Wt[0], A[o], s);
    s = __builtin_elementwise_fma(Wt[5], B[o + 2], s);
    s = __builtin_elementwise_fma(Wt[4], B[o + 1], s);
    s = __builtin_elementwise_fma(Wt[3], B[o], s);
    s = __builtin_elementwise_fma(Wt[8], Cc[o + 2], s);
    s = __builtin_elementwise_fma(Wt[7], Cc[o + 1], s);
    s = __builtin_elementwise_fma(Wt[6], Cc[o], s);
    return s;
}

__global__ __launch_bounds__(256, 3) void moe_kernel(const float* __restrict__ x,
                                                     const float* __restrict__ ew1,
                                                     const float* __restrict__ eb1,
                                                     const float* __restrict__ ew2,
                                                     const float* __restrict__ eb2,
                                                     const float* __restrict__ cof,
                                                     float* __restrict__ out) {
    __shared__ float xs[XROWS * SW];     // 36*200*4 = 28800 B
    const int sb = blockIdx.x;           // stripe 0..5
    const int c = blockIdx.y;
    const int b = blockIdx.z;
    const int ty0 = sb * TY;
    const int tid = threadIdx.x;
    const int lane = tid & 63;
    const int wv = tid >> 6;

    // ---- zero the 4-col aprons (xi 0..3 and 196..199), one b128 each ----
    if (tid < 2 * XROWS) {
        int r = tid >> 1;
        int side = tid & 1;
        *(float4*)&xs[r * SW + side * 196] = make_float4(0.f, 0.f, 0.f, 0.f);
    }

    // ---- stage 36 rows x 192 cols as float4 (48 per row), flat over 256 threads ----
    const float* xp = x + ((size_t)(b * DIM + c)) * HW;
    #pragma unroll
    for (int it = 0; it < 7; ++it) {
        int f = tid + it * 256;
        if (f < XROWS * 48) {
            int r = f / 48;
            int k = f - r * 48;
            int gh = ty0 + r - 2;
            float4 v = make_float4(0.f, 0.f, 0.f, 0.f);
            if (gh >= 0 && gh < H) v = *(const float4*)(xp + (size_t)gh * W + k * 4);
            *(float4*)&xs[r * SW + 4 + k * 4] = v;
        }
    }

    // ---- compact the (always exactly 3) chosen experts; hoist to SGPR ----
    const float* cofb = cof + b * NE;
    int e0 = 0, e1 = 0, e2 = 0;
    float q0 = 0.f, q1 = 0.f, q2 = 0.f;
    int n = 0;
    #pragma unroll
    for (int e = 0; e < NE; ++e) {
        float ce = cofb[e];
        if (ce != 0.f) {
            if (n == 0)      { e0 = e; q0 = ce; }
            else if (n == 1) { e1 = e; q1 = ce; }
            else if (n == 2) { e2 = e; q2 = ce; }
            ++n;
        }
    }
    e0 = __builtin_amdgcn_readfirstlane(e0);
    e1 = __builtin_amdgcn_readfirstlane(e1);
    e2 = __builtin_amdgcn_readfirstlane(e2);
    q0 = __int_as_float(__builtin_amdgcn_readfirstlane(__float_as_int(q0)));
    q1 = __int_as_float(__builtin_amdgcn_readfirstlane(__float_as_int(q1)));
    q2 = __int_as_float(__builtin_amdgcn_readfirstlane(__float_as_int(q2)));

    // weights: pair (e0,e1) packed, e2 scalar
    f2 W1p[9], W2p[9];
    float W1s[9], W2s[9];
    {
        const float* p10 = ew1 + (size_t)(e0 * DIM + c) * 9;
        const float* p11 = ew1 + (size_t)(e1 * DIM + c) * 9;
        const float* p12 = ew1 + (size_t)(e2 * DIM + c) * 9;
        const float* p20 = ew2 + (size_t)(e0 * DIM + c) * 9;
        const float* p21 = ew2 + (size_t)(e1 * DIM + c) * 9;
        const float* p22 = ew2 + (size_t)(e2 * DIM + c) * 9;
        #pragma unroll
        for (int k = 0; k < 9; ++k) {
            W1p[k].x = p10[k]; W1p[k].y = p11[k]; W1s[k] = p12[k];
            W2p[k].x = p20[k]; W2p[k].y = p21[k]; W2s[k] = p22[k];
        }
    }
    f2 B1p, B2p;
    B1p.x = eb1[e0 * DIM + c]; B1p.y = eb1[e1 * DIM + c];
    B2p.x = eb2[e0 * DIM + c]; B2p.y = eb2[e1 * DIM + c];
    const float B1s = eb1[e2 * DIM + c];
    const float B2s = eb2[e2 * DIM + c];
    const float CE0 = q0, CE1 = q1, CE2 = q2;

    __syncthreads();                     // xs staged (single barrier in kernel)

    const int r0 = ty0 + wv * RPW;       // first conv2 output row of this wave
    const int lbase = (wv * RPW) * SW + 3 * lane + 3;  // xs idx of col (3*lane-1), row r0-2
    const bool l0 = (lane == 0);
    const bool l63 = (lane == 63);

    float X[3][5];                       // xs window: 3 rows x 5 cols (3c-1..3c+3)
    f2 Yp[3][5];                         // pair-expert ys window: 3 rows x 5 cols
    float Ysc[3][5];                     // scalar-expert ys window
    #pragma unroll
    for (int k = 0; k < 5; ++k) X[0][k] = xs[lbase + k];           // row r0-2
    #pragma unroll
    for (int k = 0; k < 5; ++k) X[1][k] = xs[lbase + SW + k];      // row r0-1

    float* op = out + ((size_t)(b * DIM + c)) * HW + (size_t)r0 * W + 3 * lane;
    const f2 zero2 = splat2(0.f);

    #pragma unroll
    for (int j = 0; j < RPW + 2; ++j) {  // ys row ry = r0-1+j; out row r0+j-2 for j>=2
        float* xN = X[(j + 2) % 3];
        #pragma unroll
        for (int k = 0; k < 5; ++k) xN[k] = xs[lbase + (j + 2) * SW + k];  // row r0+j
        const float* xA = X[j % 3];          // row ry-1
        const float* xB = X[(j + 1) % 3];    // row ry
        const float* xC = xN;                // row ry+1

        // conv1 + bias + relu
        f2 y0p = c3p(W1p, B1p, xA, xB, xC, 0);
        f2 y1p = c3p(W1p, B1p, xA, xB, xC, 1);
        f2 y2p = c3p(W1p, B1p, xA, xB, xC, 2);
        float y0s = c3(W1s, B1s, xA, xB, xC, 0);
        float y1s = c3(W1s, B1s, xA, xB, xC, 1);
        float y2s = c3(W1s, B1s, xA, xB, xC, 2);
        y0p = __builtin_elementwise_max(y0p, zero2);
        y1p = __builtin_elementwise_max(y1p, zero2);
        y2p = __builtin_elementwise_max(y2p, zero2);
        y0s = fmaxf(y0s, 0.f); y1s = fmaxf(y1s, 0.f); y2s = fmaxf(y2s, 0.f);
        if (j == 0 || j == RPW + 1) {        // only edge rows can be out of image
            int ry = r0 - 1 + j;
            if (ry < 0 || ry >= H) {
                y0p = zero2; y1p = zero2; y2p = zero2;
                y0s = 0.f; y1s = 0.f; y2s = 0.f;  // conv2 zero-pad
            }
        }
        // halo columns via shuffles (per expert half)
        float ylpx = __shfl_up(y2p.x, 1), ylpy = __shfl_up(y2p.y, 1);
        float yls = __shfl_up(y2s, 1);
        float yrpx = __shfl_down(y0p.x, 1), yrpy = __shfl_down(y0p.y, 1);
        float yrs = __shfl_down(y0s, 1);
        if (l0)  { ylpx = 0.f; ylpy = 0.f; yls = 0.f; }   // ys col -1 == 0
        if (l63) { yrpx = 0.f; yrpy = 0.f; yrs = 0.f; }   // ys col 192 == 0
        f2* ywp = Yp[j % 3];
        float* yws = Ysc[j % 3];
        ywp[0].x = ylpx; ywp[0].y = ylpy;
        ywp[1] = y0p; ywp[2] = y1p; ywp[3] = y2p;
        ywp[4].x = yrpx; ywp[4].y = yrpy;
        yws[0] = yls; yws[1] = y0s; yws[2] = y1s; yws[3] = y2s; yws[4] = yrs;

        if (j >= 2) {
            const f2* pA = Yp[(j + 1) % 3];      // ys row ro-1
            const f2* pB = Yp[(j + 2) % 3];      // ys row ro
            const f2* pC = ywp;                  // ys row ro+1
            const float* sA = Ysc[(j + 1) % 3];
            const float* sB = Ysc[(j + 2) % 3];
            const float* sC = yws;
            f2 s0p = c3q(W2p, B2p, pA, pB, pC, 0);
            f2 s1p = c3q(W2p, B2p, pA, pB, pC, 1);
            f2 s2p = c3q(W2p, B2p, pA, pB, pC, 2);
            float s0s = c3(W2s, B2s, sA, sB, sC, 0);
            float s1s = c3(W2s, B2s, sA, sB, sC, 1);
            float s2s = c3(W2s, B2s, sA, sB, sC, 2);
            // accumulate in the SAME order as v2: e0, e1, e2 fma chain
            float a0 = fmaf(CE2, s0s, fmaf(CE1, s0p.y, fmaf(CE0, s0p.x, 0.f)));
            float a1 = fmaf(CE2, s1s, fmaf(CE1, s1p.y, fmaf(CE0, s1p.x, 0.f)));
            float a2 = fmaf(CE2, s2s, fmaf(CE1, s2p.y, fmaf(CE0, s2p.x, 0.f)));
            op[0] = a0; op[1] = a1; op[2] = a2;
            op += W;
        }
    }
}

extern "C" void kernel_launch(void* const* d_in, const int* in_sizes, int n_in,
                              void* d_out, int out_size, void* d_ws, size_t ws_size,
                              hipStream_t stream) {
    const float* x     = (const float*)d_in[0];
    const float* w_fc0 = (const float*)d_in[1];
    const float* b_fc0 = (const float*)d_in[2];
    const float* w_fc1 = (const float*)d_in[3];
    const float* b_fc1 = (const float*)d_in[4];
    const float* ew1   = (const float*)d_in[5];
    const float* eb1   = (const float*)d_in[6];
    const float* ew2   = (const float*)d_in[7];
    const float* eb2   = (const float*)d_in[8];
    float* out = (float*)d_out;

    float* pmax = (float*)d_ws;                       // NQ*768
    float* psum = pmax + NQ * NB * DIM;               // NQ*768
    float* cof  = psum + NQ * NB * DIM;               // 48

    dim3 pg(NB * DIM, NQ);
    pool_partial<<<pg, 256, 0, stream>>>(x, pmax, psum);
    gate_kernel<<<1, 128, 0, stream>>>(pmax, psum, w_fc0, b_fc0, w_fc1, b_fc1, cof);
    dim3 grid(H / TY, DIM, NB);                       // (6, 96, 8)
    moe_kernel<<<grid, 256, 0, stream>>>(x, ew1, eb1, ew2, eb2, cof, out);
}